// Round 8
// baseline (396.896 us; speedup 1.0000x reference)
//
#include <hip/hip_runtime.h>

#define NUM_USERS 25000
#define NUM_ITEMS 25000
#define N_NODES   50000
#define N_EDGES   800000
#define K         64
#define N_QUERY   4096
#define LRELU     0.2f

#define NCHUNK 256
#define CHSZ   196          // 256*196 = 50176 >= 50000

typedef unsigned short ushort_t;

// out layout: [ xui (4096) | gu (25000 x 256) | gi (25000 x 256) ]
__device__ __forceinline__ size_t node_out_offset(int n) {
    return (size_t)N_QUERY + (size_t)n * 256;
}

// f32 -> bf16 round-to-nearest-even
__device__ __forceinline__ ushort_t f2bf(float x) {
    unsigned u = __float_as_uint(x);
    return (ushort_t)((u + 0x7FFFu + ((u >> 16) & 1u)) >> 16);
}
__device__ __forceinline__ float bf2f(ushort_t v) {
    return __uint_as_float(((unsigned)v) << 16);
}

// ---------------------------------------------------------------------------
// init: ego(f32+bf16) = concat(Gu0, Gi0); layer-0 block of out
// ---------------------------------------------------------------------------
__global__ __launch_bounds__(256) void init_ego_kernel(
    const float* __restrict__ Gu0, const float* __restrict__ Gi0,
    float* __restrict__ ego, ushort_t* __restrict__ egb, float* __restrict__ out)
{
    int tid = blockIdx.x * 256 + threadIdx.x;
    if (tid >= N_NODES * K) return;
    int n = tid >> 6;
    int d = tid & 63;
    float v = (n < NUM_USERS) ? Gu0[tid] : Gi0[tid - NUM_USERS * K];
    ego[tid] = v;
    egb[tid] = f2bf(v);
    out[node_out_offset(n) + d] = v;
}

// ---------------------------------------------------------------------------
// weight transpose: WT[k][m][o][j] = W_m[k][j][o]
// ---------------------------------------------------------------------------
__global__ __launch_bounds__(256) void wtrans_kernel(
    const float* __restrict__ W_gc, const float* __restrict__ W_bi,
    float* __restrict__ WT)
{
    int tid = blockIdx.x * 256 + threadIdx.x;
    if (tid >= 3 * 2 * 64 * 64) return;
    int k   = tid >> 13;
    int m   = (tid >> 12) & 1;
    int idx = tid & 4095;
    int o   = idx >> 6;
    int j   = idx & 63;
    const float* src = m ? W_bi : W_gc;
    WT[tid] = src[k * 4096 + j * 64 + o];
}

// ---------------------------------------------------------------------------
// CSR build: histogram
// ---------------------------------------------------------------------------
__global__ __launch_bounds__(256) void count_kernel(
    const int* __restrict__ rows, int* __restrict__ counts)
{
    int e = blockIdx.x * 256 + threadIdx.x;
    if (e >= N_EDGES) return;
    atomicAdd(&counts[rows[e]], 1);
}

__global__ __launch_bounds__(256) void s1_kernel(
    const int* __restrict__ counts, int* __restrict__ bsum)
{
    __shared__ int red[256];
    int b = blockIdx.x, t = threadIdx.x;
    int idx = b * CHSZ + t;
    int v = (t < CHSZ && idx < N_NODES) ? counts[idx] : 0;
    red[t] = v;
    __syncthreads();
    for (int off = 128; off; off >>= 1) {
        if (t < off) red[t] += red[t + off];
        __syncthreads();
    }
    if (t == 0) bsum[b] = red[0];
}

__global__ __launch_bounds__(256) void s2_kernel(int* __restrict__ bsum)
{
    __shared__ int sh[256];
    int t = threadIdx.x;
    sh[t] = bsum[t];
    __syncthreads();
    for (int off = 1; off < 256; off <<= 1) {
        int v = (t >= off) ? sh[t - off] : 0;
        __syncthreads();
        sh[t] += v;
        __syncthreads();
    }
    bsum[t] = (t == 0) ? 0 : sh[t - 1];
}

__global__ __launch_bounds__(256) void s3_kernel(
    const int* __restrict__ counts, const int* __restrict__ bsum,
    int* __restrict__ offs, int* __restrict__ cursor)
{
    __shared__ int sh[256];
    int b = blockIdx.x, t = threadIdx.x;
    int idx = b * CHSZ + t;
    int v = (t < CHSZ && idx < N_NODES) ? counts[idx] : 0;
    sh[t] = v;
    __syncthreads();
    for (int off = 1; off < 256; off <<= 1) {
        int x = (t >= off) ? sh[t - off] : 0;
        __syncthreads();
        sh[t] += x;
        __syncthreads();
    }
    int excl = bsum[b] + sh[t] - v;
    if (t < CHSZ && idx < N_NODES) {
        offs[idx]   = excl;
        cursor[idx] = excl;
    }
    if (b == 0 && t == 0) offs[N_NODES] = N_EDGES;
}

// scatter edge INDEX into row-sorted order (4B random writes, L2-resident)
__global__ __launch_bounds__(256) void scatter_kernel(
    const int* __restrict__ rows, int* __restrict__ cursor,
    int* __restrict__ perm)
{
    int e = blockIdx.x * 256 + threadIdx.x;
    if (e >= N_EDGES) return;
    int r = rows[e];
    int pos = atomicAdd(&cursor[r], 1);
    perm[pos] = e;
}

// ---------------------------------------------------------------------------
// gather: side[n][lane] = sum_e val_e * ego_bf16[col_e][lane] (f32 accumulate)
// Edge stream via perm indirection: perm[j] -> e -> cols[e], vals[e] (L2
// broadcast reads), ego row as bf16 (128B/row, halves L3 traffic).
// 512 threads = 8 waves = 8 nodes/block; grid 6250. 12-deep ILP.
// ---------------------------------------------------------------------------
__global__ __launch_bounds__(512, 8) void gather_kernel(
    const int* __restrict__ offs, const int* __restrict__ perm,
    const int* __restrict__ cols, const float* __restrict__ vals,
    const ushort_t* __restrict__ egb, float* __restrict__ side)
{
    int t = threadIdx.x;
    int wave = t >> 6;
    int lane = t & 63;
    int node = blockIdx.x * 8 + wave;

    int beg = offs[node];
    int end = offs[node + 1];
    float acc = 0.f;
    int j = beg;

    for (; j + 12 <= end; j += 12) {
        int ee[12];
        #pragma unroll
        for (int u = 0; u < 12; ++u) ee[u] = perm[j + u];
        int   cc[12];
        float vv[12];
        #pragma unroll
        for (int u = 0; u < 12; ++u) { cc[u] = cols[ee[u]]; vv[u] = vals[ee[u]]; }
        float gg[12];
        #pragma unroll
        for (int u = 0; u < 12; ++u)
            gg[u] = bf2f(egb[((size_t)cc[u] << 6) + lane]);
        #pragma unroll
        for (int u = 0; u < 12; ++u) acc = fmaf(vv[u], gg[u], acc);
    }
    for (; j + 4 <= end; j += 4) {
        int ee[4];
        #pragma unroll
        for (int u = 0; u < 4; ++u) ee[u] = perm[j + u];
        int   cc[4];
        float vv[4];
        #pragma unroll
        for (int u = 0; u < 4; ++u) { cc[u] = cols[ee[u]]; vv[u] = vals[ee[u]]; }
        float gg[4];
        #pragma unroll
        for (int u = 0; u < 4; ++u)
            gg[u] = bf2f(egb[((size_t)cc[u] << 6) + lane]);
        #pragma unroll
        for (int u = 0; u < 4; ++u) acc = fmaf(vv[u], gg[u], acc);
    }
    for (; j < end; ++j) {
        int e = perm[j];
        acc = fmaf(vals[e], bf2f(egb[((size_t)cols[e] << 6) + lane]), acc);
    }

    side[((size_t)node << 6) + lane] = acc;
}

// ---------------------------------------------------------------------------
// transform: register-tiled f32 GEMM (64 nodes x 64 outs, K=64), 4x4
// micro-tile, XOR-swizzled LDS. Epilogue: bias+lrelu+add, 16-lane norm,
// writes ego(f32), ego(bf16), out.
// ---------------------------------------------------------------------------
__global__ __launch_bounds__(256, 2) void transform_kernel(
    const float* __restrict__ side, float* __restrict__ ego,
    ushort_t* __restrict__ egb,
    const float* __restrict__ WgT, const float* __restrict__ WbT,
    const float* __restrict__ bgc, const float* __restrict__ bbi,
    float* __restrict__ out, int layer_k)
{
    __shared__ float s_s [64 * 64];
    __shared__ float s_es[64 * 64];
    __shared__ float s_wg[64 * 64];
    __shared__ float s_wb[64 * 64];

    int t = threadIdx.x;
    int base = blockIdx.x * 64;

    for (int idx = t; idx < 64 * 16; idx += 256) {
        int r = idx >> 4;
        int q = idx & 15;
        int qs = q ^ ((r >> 2) & 7);
        float4 sv = make_float4(0.f, 0.f, 0.f, 0.f);
        float4 ev = make_float4(0.f, 0.f, 0.f, 0.f);
        int node = base + r;
        if (node < N_NODES) {
            sv = *(const float4*)(side + ((size_t)node << 6) + 4 * q);
            ev = *(const float4*)(ego  + ((size_t)node << 6) + 4 * q);
        }
        *(float4*)&s_s [r * 64 + 4 * qs] = sv;
        *(float4*)&s_es[r * 64 + 4 * qs] =
            make_float4(ev.x * sv.x, ev.y * sv.y, ev.z * sv.z, ev.w * sv.w);
        *(float4*)&s_wg[r * 64 + 4 * qs] = *(const float4*)(WgT + (size_t)r * 64 + 4 * q);
        *(float4*)&s_wb[r * 64 + 4 * qs] = *(const float4*)(WbT + (size_t)r * 64 + 4 * q);
    }
    __syncthreads();

    const int o0  = (t & 15) << 2;
    const int ln0 = (t >> 4) << 2;
    const int sa  = (t >> 4) & 7;
    const int sw  = t & 7;

    float accg[4][4] = {};
    float accb[4][4] = {};

    #pragma unroll 4
    for (int kq = 0; kq < 16; ++kq) {
        const int qa = (kq ^ sa) << 2;
        const int qw = (kq ^ sw) << 2;
        float4 a[4], b[4], wg[4], wb[4];
        #pragma unroll
        for (int i = 0; i < 4; ++i) {
            a[i] = *(const float4*)&s_s [(ln0 + i) * 64 + qa];
            b[i] = *(const float4*)&s_es[(ln0 + i) * 64 + qa];
        }
        #pragma unroll
        for (int j = 0; j < 4; ++j) {
            wg[j] = *(const float4*)&s_wg[(o0 + j) * 64 + qw];
            wb[j] = *(const float4*)&s_wb[(o0 + j) * 64 + qw];
        }
        #pragma unroll
        for (int i = 0; i < 4; ++i) {
            #pragma unroll
            for (int j = 0; j < 4; ++j) {
                accg[i][j] = fmaf(a[i].x, wg[j].x, accg[i][j]);
                accg[i][j] = fmaf(a[i].y, wg[j].y, accg[i][j]);
                accg[i][j] = fmaf(a[i].z, wg[j].z, accg[i][j]);
                accg[i][j] = fmaf(a[i].w, wg[j].w, accg[i][j]);
                accb[i][j] = fmaf(b[i].x, wb[j].x, accb[i][j]);
                accb[i][j] = fmaf(b[i].y, wb[j].y, accb[i][j]);
                accb[i][j] = fmaf(b[i].z, wb[j].z, accb[i][j]);
                accb[i][j] = fmaf(b[i].w, wb[j].w, accb[i][j]);
            }
        }
    }

    float4 bg4 = *(const float4*)(bgc + o0);
    float4 bb4 = *(const float4*)(bbi + o0);
    float bgv[4] = {bg4.x, bg4.y, bg4.z, bg4.w};
    float bbv[4] = {bb4.x, bb4.y, bb4.z, bb4.w};

    #pragma unroll
    for (int i = 0; i < 4; ++i) {
        int node = base + ln0 + i;
        float en[4];
        float ss = 0.f;
        #pragma unroll
        for (int j = 0; j < 4; ++j) {
            float g = accg[i][j] + bgv[j];
            float h = accb[i][j] + bbv[j];
            g = (g > 0.f) ? g : LRELU * g;
            h = (h > 0.f) ? h : LRELU * h;
            en[j] = g + h;
            ss = fmaf(en[j], en[j], ss);
        }
        #pragma unroll
        for (int m = 1; m < 16; m <<= 1) ss += __shfl_xor(ss, m);
        float inv = rsqrtf(fmaxf(ss, 1e-12f));
        if (node < N_NODES) {
            *(float4*)(ego + ((size_t)node << 6) + o0) =
                make_float4(en[0], en[1], en[2], en[3]);
            *(ushort4*)(egb + ((size_t)node << 6) + o0) =
                make_ushort4(f2bf(en[0]), f2bf(en[1]), f2bf(en[2]), f2bf(en[3]));
            *(float4*)(out + node_out_offset(node) + (size_t)(layer_k + 1) * K + o0) =
                make_float4(en[0] * inv, en[1] * inv, en[2] * inv, en[3] * inv);
        }
    }
}

// ---------------------------------------------------------------------------
// readout: xui[i] = dot(gu[user[i]], gi[item[i]]) over 256 dims
// ---------------------------------------------------------------------------
__global__ __launch_bounds__(256) void xui_kernel(
    const int* __restrict__ user, const int* __restrict__ item,
    float* __restrict__ out)
{
    int idx = blockIdx.x * 4 + (threadIdx.x >> 6);
    if (idx >= N_QUERY) return;
    int lane = threadIdx.x & 63;
    int u  = user[idx];
    int it = item[idx];
    const float4* gu = (const float4*)(out + (size_t)N_QUERY + (size_t)u * 256);
    const float4* gi = (const float4*)(out + (size_t)N_QUERY + (size_t)NUM_USERS * 256
                                           + (size_t)it * 256);
    float4 a = gu[lane];
    float4 b = gi[lane];
    float d = a.x * b.x + a.y * b.y + a.z * b.z + a.w * b.w;
    #pragma unroll
    for (int off = 32; off; off >>= 1) d += __shfl_xor(d, off);
    if (lane == 0) out[idx] = d;
}

extern "C" void kernel_launch(void* const* d_in, const int* in_sizes, int n_in,
                              void* d_out, int out_size, void* d_ws, size_t ws_size,
                              hipStream_t stream)
{
    const int*   adj_rows = (const int*)  d_in[0];
    const int*   adj_cols = (const int*)  d_in[1];
    const float* adj_vals = (const float*)d_in[2];
    const float* Gu0      = (const float*)d_in[3];
    const float* Gi0      = (const float*)d_in[4];
    const float* W_gc     = (const float*)d_in[5];
    const float* b_gc     = (const float*)d_in[6];
    const float* W_bi     = (const float*)d_in[7];
    const float* b_bi     = (const float*)d_in[8];
    const int*   user     = (const int*)  d_in[9];
    const int*   item     = (const int*)  d_in[10];

    float* out = (float*)d_out;

    // workspace (~35.8 MB):
    float*    ego  = (float*)d_ws;                              // 12.8 MB
    float*    side = ego + (size_t)N_NODES * K;                 // 12.8 MB
    ushort_t* egb  = (ushort_t*)(side + (size_t)N_NODES * K);   // 6.4 MB (bf16 ego)
    int*      perm = (int*)(egb + (size_t)N_NODES * K);         // 3.2 MB
    int*      offs = perm + N_EDGES;                            // N_NODES+1
    int*      cnt  = offs + N_NODES + 1;                        // N_NODES
    int*      bsum = cnt + N_NODES;                             // 256
    float*    WT   = (float*)(bsum + NCHUNK);                   // 96 KB

    // ---- CSR build (perm only) ----
    hipMemsetAsync(cnt, 0, N_NODES * sizeof(int), stream);
    count_kernel<<<(N_EDGES + 255) / 256, 256, 0, stream>>>(adj_rows, cnt);
    s1_kernel<<<NCHUNK, 256, 0, stream>>>(cnt, bsum);
    s2_kernel<<<1, 256, 0, stream>>>(bsum);
    s3_kernel<<<NCHUNK, 256, 0, stream>>>(cnt, bsum, offs, cnt);
    scatter_kernel<<<(N_EDGES + 255) / 256, 256, 0, stream>>>(adj_rows, cnt, perm);

    // ---- weight transpose + init ego ----
    wtrans_kernel<<<(3 * 2 * 4096 + 255) / 256, 256, 0, stream>>>(W_gc, W_bi, WT);
    init_ego_kernel<<<(N_NODES * K + 255) / 256, 256, 0, stream>>>(Gu0, Gi0, ego, egb, out);

    // ---- 3 layers ----
    for (int k = 0; k < 3; ++k) {
        gather_kernel<<<N_NODES / 8, 512, 0, stream>>>(
            offs, perm, adj_cols, adj_vals, egb, side);
        transform_kernel<<<(N_NODES + 63) / 64, 256, 0, stream>>>(
            side, ego, egb,
            WT + (size_t)k * 8192, WT + (size_t)k * 8192 + 4096,
            b_gc + (size_t)k * K, b_bi + (size_t)k * K,
            out, k);
    }

    xui_kernel<<<N_QUERY / 4, 256, 0, stream>>>(user, item, out);
}

// Round 9
// 321.640 us; speedup vs baseline: 1.2340x; 1.2340x over previous
//
#include <hip/hip_runtime.h>

#define NUM_USERS 25000
#define NUM_ITEMS 25000
#define N_NODES   50000
#define N_EDGES   800000
#define K         64
#define N_QUERY   4096
#define LRELU     0.2f

#define NCHUNK 256
#define CHSZ   196          // 256*196 = 50176 >= 50000

typedef unsigned short ushort_t;

// out layout: [ xui (4096) | gu (25000 x 256) | gi (25000 x 256) ]
__device__ __forceinline__ size_t node_out_offset(int n) {
    return (size_t)N_QUERY + (size_t)n * 256;
}

// f32 -> bf16 round-to-nearest-even
__device__ __forceinline__ ushort_t f2bf(float x) {
    unsigned u = __float_as_uint(x);
    return (ushort_t)((u + 0x7FFFu + ((u >> 16) & 1u)) >> 16);
}
__device__ __forceinline__ float bf2f(ushort_t v) {
    return __uint_as_float(((unsigned)v) << 16);
}

// ---------------------------------------------------------------------------
// init: ego(f32+bf16) = concat(Gu0, Gi0); layer-0 block of out
// ---------------------------------------------------------------------------
__global__ __launch_bounds__(256) void init_ego_kernel(
    const float* __restrict__ Gu0, const float* __restrict__ Gi0,
    float* __restrict__ ego, ushort_t* __restrict__ egb, float* __restrict__ out)
{
    int tid = blockIdx.x * 256 + threadIdx.x;
    if (tid >= N_NODES * K) return;
    int n = tid >> 6;
    int d = tid & 63;
    float v = (n < NUM_USERS) ? Gu0[tid] : Gi0[tid - NUM_USERS * K];
    ego[tid] = v;
    egb[tid] = f2bf(v);
    out[node_out_offset(n) + d] = v;
}

// ---------------------------------------------------------------------------
// weight transpose: WT[k][m][o][j] = W_m[k][j][o]
// ---------------------------------------------------------------------------
__global__ __launch_bounds__(256) void wtrans_kernel(
    const float* __restrict__ W_gc, const float* __restrict__ W_bi,
    float* __restrict__ WT)
{
    int tid = blockIdx.x * 256 + threadIdx.x;
    if (tid >= 3 * 2 * 64 * 64) return;
    int k   = tid >> 13;
    int m   = (tid >> 12) & 1;
    int idx = tid & 4095;
    int o   = idx >> 6;
    int j   = idx & 63;
    const float* src = m ? W_bi : W_gc;
    WT[tid] = src[k * 4096 + j * 64 + o];
}

// ---------------------------------------------------------------------------
// CSR build: histogram
// ---------------------------------------------------------------------------
__global__ __launch_bounds__(256) void count_kernel(
    const int* __restrict__ rows, int* __restrict__ counts)
{
    int e = blockIdx.x * 256 + threadIdx.x;
    if (e >= N_EDGES) return;
    atomicAdd(&counts[rows[e]], 1);
}

__global__ __launch_bounds__(256) void s1_kernel(
    const int* __restrict__ counts, int* __restrict__ bsum)
{
    __shared__ int red[256];
    int b = blockIdx.x, t = threadIdx.x;
    int idx = b * CHSZ + t;
    int v = (t < CHSZ && idx < N_NODES) ? counts[idx] : 0;
    red[t] = v;
    __syncthreads();
    for (int off = 128; off; off >>= 1) {
        if (t < off) red[t] += red[t + off];
        __syncthreads();
    }
    if (t == 0) bsum[b] = red[0];
}

__global__ __launch_bounds__(256) void s2_kernel(int* __restrict__ bsum)
{
    __shared__ int sh[256];
    int t = threadIdx.x;
    sh[t] = bsum[t];
    __syncthreads();
    for (int off = 1; off < 256; off <<= 1) {
        int v = (t >= off) ? sh[t - off] : 0;
        __syncthreads();
        sh[t] += v;
        __syncthreads();
    }
    bsum[t] = (t == 0) ? 0 : sh[t - 1];
}

__global__ __launch_bounds__(256) void s3_kernel(
    const int* __restrict__ counts, const int* __restrict__ bsum,
    int* __restrict__ offs, int* __restrict__ cursor)
{
    __shared__ int sh[256];
    int b = blockIdx.x, t = threadIdx.x;
    int idx = b * CHSZ + t;
    int v = (t < CHSZ && idx < N_NODES) ? counts[idx] : 0;
    sh[t] = v;
    __syncthreads();
    for (int off = 1; off < 256; off <<= 1) {
        int x = (t >= off) ? sh[t - off] : 0;
        __syncthreads();
        sh[t] += x;
        __syncthreads();
    }
    int excl = bsum[b] + sh[t] - v;
    if (t < CHSZ && idx < N_NODES) {
        offs[idx]   = excl;
        cursor[idx] = excl;
    }
    if (b == 0 && t == 0) offs[N_NODES] = N_EDGES;
}

// scatter edges into row-sorted order, packed (col, val) 8B
__global__ __launch_bounds__(256) void scatter_kernel(
    const int* __restrict__ rows, const int* __restrict__ cols,
    const float* __restrict__ vals, int* __restrict__ cursor,
    int2* __restrict__ csr_cv)
{
    int e = blockIdx.x * 256 + threadIdx.x;
    if (e >= N_EDGES) return;
    int r = rows[e];
    int pos = atomicAdd(&cursor[r], 1);
    csr_cv[pos] = make_int2(cols[e], __float_as_int(vals[e]));
}

// ---------------------------------------------------------------------------
// gather: side[n][lane] = sum_e val_e * ego_bf16[col_e][lane] (f32 accum).
// csr_cv sequential 8B stream (nontemporal); ego rows bf16 (128B, ~L2-resident).
// 512 threads = 8 waves = 8 nodes/block; grid 6250. 12-deep ILP.
// ---------------------------------------------------------------------------
__global__ __launch_bounds__(512, 8) void gather_kernel(
    const int* __restrict__ offs, const long long* __restrict__ csr_cv,
    const ushort_t* __restrict__ egb, float* __restrict__ side)
{
    int t = threadIdx.x;
    int wave = t >> 6;
    int lane = t & 63;
    int node = blockIdx.x * 8 + wave;

    int beg = offs[node];
    int end = offs[node + 1];
    float acc = 0.f;
    int j = beg;

    for (; j + 12 <= end; j += 12) {
        long long cvp[12];
        #pragma unroll
        for (int u = 0; u < 12; ++u) cvp[u] = __builtin_nontemporal_load(csr_cv + j + u);
        float gg[12];
        #pragma unroll
        for (int u = 0; u < 12; ++u)
            gg[u] = bf2f(egb[((size_t)(unsigned int)(cvp[u] & 0xffffffffLL) << 6) + lane]);
        #pragma unroll
        for (int u = 0; u < 12; ++u)
            acc = fmaf(__uint_as_float((unsigned int)((unsigned long long)cvp[u] >> 32)), gg[u], acc);
    }
    for (; j + 4 <= end; j += 4) {
        long long cvp[4];
        #pragma unroll
        for (int u = 0; u < 4; ++u) cvp[u] = __builtin_nontemporal_load(csr_cv + j + u);
        float gg[4];
        #pragma unroll
        for (int u = 0; u < 4; ++u)
            gg[u] = bf2f(egb[((size_t)(unsigned int)(cvp[u] & 0xffffffffLL) << 6) + lane]);
        #pragma unroll
        for (int u = 0; u < 4; ++u)
            acc = fmaf(__uint_as_float((unsigned int)((unsigned long long)cvp[u] >> 32)), gg[u], acc);
    }
    for (; j < end; ++j) {
        long long cvp = __builtin_nontemporal_load(csr_cv + j);
        acc = fmaf(__uint_as_float((unsigned int)((unsigned long long)cvp >> 32)),
                   bf2f(egb[((size_t)(unsigned int)(cvp & 0xffffffffLL) << 6) + lane]), acc);
    }

    side[((size_t)node << 6) + lane] = acc;
}

// ---------------------------------------------------------------------------
// transform: register-tiled f32 GEMM (64 nodes x 64 outs, K=64), 4x4
// micro-tile, XOR-swizzled LDS. Epilogue: bias+lrelu+add, 16-lane norm,
// writes ego(f32), egb(bf16), out.
// ---------------------------------------------------------------------------
__global__ __launch_bounds__(256, 2) void transform_kernel(
    const float* __restrict__ side, float* __restrict__ ego,
    ushort_t* __restrict__ egb,
    const float* __restrict__ WgT, const float* __restrict__ WbT,
    const float* __restrict__ bgc, const float* __restrict__ bbi,
    float* __restrict__ out, int layer_k)
{
    __shared__ float s_s [64 * 64];
    __shared__ float s_es[64 * 64];
    __shared__ float s_wg[64 * 64];
    __shared__ float s_wb[64 * 64];

    int t = threadIdx.x;
    int base = blockIdx.x * 64;

    for (int idx = t; idx < 64 * 16; idx += 256) {
        int r = idx >> 4;
        int q = idx & 15;
        int qs = q ^ ((r >> 2) & 7);
        float4 sv = make_float4(0.f, 0.f, 0.f, 0.f);
        float4 ev = make_float4(0.f, 0.f, 0.f, 0.f);
        int node = base + r;
        if (node < N_NODES) {
            sv = *(const float4*)(side + ((size_t)node << 6) + 4 * q);
            ev = *(const float4*)(ego  + ((size_t)node << 6) + 4 * q);
        }
        *(float4*)&s_s [r * 64 + 4 * qs] = sv;
        *(float4*)&s_es[r * 64 + 4 * qs] =
            make_float4(ev.x * sv.x, ev.y * sv.y, ev.z * sv.z, ev.w * sv.w);
        *(float4*)&s_wg[r * 64 + 4 * qs] = *(const float4*)(WgT + (size_t)r * 64 + 4 * q);
        *(float4*)&s_wb[r * 64 + 4 * qs] = *(const float4*)(WbT + (size_t)r * 64 + 4 * q);
    }
    __syncthreads();

    const int o0  = (t & 15) << 2;
    const int ln0 = (t >> 4) << 2;
    const int sa  = (t >> 4) & 7;
    const int sw  = t & 7;

    float accg[4][4] = {};
    float accb[4][4] = {};

    #pragma unroll 4
    for (int kq = 0; kq < 16; ++kq) {
        const int qa = (kq ^ sa) << 2;
        const int qw = (kq ^ sw) << 2;
        float4 a[4], b[4], wg[4], wb[4];
        #pragma unroll
        for (int i = 0; i < 4; ++i) {
            a[i] = *(const float4*)&s_s [(ln0 + i) * 64 + qa];
            b[i] = *(const float4*)&s_es[(ln0 + i) * 64 + qa];
        }
        #pragma unroll
        for (int j = 0; j < 4; ++j) {
            wg[j] = *(const float4*)&s_wg[(o0 + j) * 64 + qw];
            wb[j] = *(const float4*)&s_wb[(o0 + j) * 64 + qw];
        }
        #pragma unroll
        for (int i = 0; i < 4; ++i) {
            #pragma unroll
            for (int j = 0; j < 4; ++j) {
                accg[i][j] = fmaf(a[i].x, wg[j].x, accg[i][j]);
                accg[i][j] = fmaf(a[i].y, wg[j].y, accg[i][j]);
                accg[i][j] = fmaf(a[i].z, wg[j].z, accg[i][j]);
                accg[i][j] = fmaf(a[i].w, wg[j].w, accg[i][j]);
                accb[i][j] = fmaf(b[i].x, wb[j].x, accb[i][j]);
                accb[i][j] = fmaf(b[i].y, wb[j].y, accb[i][j]);
                accb[i][j] = fmaf(b[i].z, wb[j].z, accb[i][j]);
                accb[i][j] = fmaf(b[i].w, wb[j].w, accb[i][j]);
            }
        }
    }

    float4 bg4 = *(const float4*)(bgc + o0);
    float4 bb4 = *(const float4*)(bbi + o0);
    float bgv[4] = {bg4.x, bg4.y, bg4.z, bg4.w};
    float bbv[4] = {bb4.x, bb4.y, bb4.z, bb4.w};

    #pragma unroll
    for (int i = 0; i < 4; ++i) {
        int node = base + ln0 + i;
        float en[4];
        float ss = 0.f;
        #pragma unroll
        for (int j = 0; j < 4; ++j) {
            float g = accg[i][j] + bgv[j];
            float h = accb[i][j] + bbv[j];
            g = (g > 0.f) ? g : LRELU * g;
            h = (h > 0.f) ? h : LRELU * h;
            en[j] = g + h;
            ss = fmaf(en[j], en[j], ss);
        }
        #pragma unroll
        for (int m = 1; m < 16; m <<= 1) ss += __shfl_xor(ss, m);
        float inv = rsqrtf(fmaxf(ss, 1e-12f));
        if (node < N_NODES) {
            *(float4*)(ego + ((size_t)node << 6) + o0) =
                make_float4(en[0], en[1], en[2], en[3]);
            *(ushort4*)(egb + ((size_t)node << 6) + o0) =
                make_ushort4(f2bf(en[0]), f2bf(en[1]), f2bf(en[2]), f2bf(en[3]));
            *(float4*)(out + node_out_offset(node) + (size_t)(layer_k + 1) * K + o0) =
                make_float4(en[0] * inv, en[1] * inv, en[2] * inv, en[3] * inv);
        }
    }
}

// ---------------------------------------------------------------------------
// readout: xui[i] = dot(gu[user[i]], gi[item[i]]) over 256 dims
// ---------------------------------------------------------------------------
__global__ __launch_bounds__(256) void xui_kernel(
    const int* __restrict__ user, const int* __restrict__ item,
    float* __restrict__ out)
{
    int idx = blockIdx.x * 4 + (threadIdx.x >> 6);
    if (idx >= N_QUERY) return;
    int lane = threadIdx.x & 63;
    int u  = user[idx];
    int it = item[idx];
    const float4* gu = (const float4*)(out + (size_t)N_QUERY + (size_t)u * 256);
    const float4* gi = (const float4*)(out + (size_t)N_QUERY + (size_t)NUM_USERS * 256
                                           + (size_t)it * 256);
    float4 a = gu[lane];
    float4 b = gi[lane];
    float d = a.x * b.x + a.y * b.y + a.z * b.z + a.w * b.w;
    #pragma unroll
    for (int off = 32; off; off >>= 1) d += __shfl_xor(d, off);
    if (lane == 0) out[idx] = d;
}

extern "C" void kernel_launch(void* const* d_in, const int* in_sizes, int n_in,
                              void* d_out, int out_size, void* d_ws, size_t ws_size,
                              hipStream_t stream)
{
    const int*   adj_rows = (const int*)  d_in[0];
    const int*   adj_cols = (const int*)  d_in[1];
    const float* adj_vals = (const float*)d_in[2];
    const float* Gu0      = (const float*)d_in[3];
    const float* Gi0      = (const float*)d_in[4];
    const float* W_gc     = (const float*)d_in[5];
    const float* b_gc     = (const float*)d_in[6];
    const float* W_bi     = (const float*)d_in[7];
    const float* b_bi     = (const float*)d_in[8];
    const int*   user     = (const int*)  d_in[9];
    const int*   item     = (const int*)  d_in[10];

    float* out = (float*)d_out;

    // workspace (~38.7 MB):
    float*     ego    = (float*)d_ws;                              // 12.8 MB
    float*     side   = ego + (size_t)N_NODES * K;                 // 12.8 MB
    ushort_t*  egb    = (ushort_t*)(side + (size_t)N_NODES * K);   // 6.4 MB
    long long* csr_cv = (long long*)(egb + (size_t)N_NODES * K);   // 6.4 MB
    int*       offs   = (int*)(csr_cv + N_EDGES);                  // N_NODES+1
    int*       cnt    = offs + N_NODES + 1;                        // N_NODES
    int*       bsum   = cnt + N_NODES;                             // 256
    float*     WT     = (float*)(bsum + NCHUNK);                   // 96 KB

    // ---- CSR build ----
    hipMemsetAsync(cnt, 0, N_NODES * sizeof(int), stream);
    count_kernel<<<(N_EDGES + 255) / 256, 256, 0, stream>>>(adj_rows, cnt);
    s1_kernel<<<NCHUNK, 256, 0, stream>>>(cnt, bsum);
    s2_kernel<<<1, 256, 0, stream>>>(bsum);
    s3_kernel<<<NCHUNK, 256, 0, stream>>>(cnt, bsum, offs, cnt);
    scatter_kernel<<<(N_EDGES + 255) / 256, 256, 0, stream>>>(
        adj_rows, adj_cols, adj_vals, cnt, (int2*)csr_cv);

    // ---- weight transpose + init ego ----
    wtrans_kernel<<<(3 * 2 * 4096 + 255) / 256, 256, 0, stream>>>(W_gc, W_bi, WT);
    init_ego_kernel<<<(N_NODES * K + 255) / 256, 256, 0, stream>>>(Gu0, Gi0, ego, egb, out);

    // ---- 3 layers ----
    for (int k = 0; k < 3; ++k) {
        gather_kernel<<<N_NODES / 8, 512, 0, stream>>>(offs, csr_cv, egb, side);
        transform_kernel<<<(N_NODES + 63) / 64, 256, 0, stream>>>(
            side, ego, egb,
            WT + (size_t)k * 8192, WT + (size_t)k * 8192 + 4096,
            b_gc + (size_t)k * K, b_bi + (size_t)k * K,
            out, k);
    }

    xui_kernel<<<N_QUERY / 4, 256, 0, stream>>>(user, item, out);
}